// Round 16
// baseline (714.322 us; speedup 1.0000x reference)
//
#include <hip/hip_runtime.h>

#define HH 256
#define WW 256
#define SS 65536   // pixels per mask; also the background sentinel label
#define NM 128     // B*K masks
#define TRR 16     // rows per tile
#define NT2 16     // tiles per mask
#define RMX 2048   // max horizontal runs in a 16x256 tile
#define SPT 1024   // max 8-conn components in a 16x256 tile
#define SPM 16384  // slots per mask (16 tiles x 1024)

// All Meta fields are written (plain stores) before any consumer reads them
// -> no init kernel despite 0xAA poison (counters zeroed by hipMemsetAsync).
struct Meta {
  double dsum[NM];                                  // written by k_top2p tail
  int h0[NM]; int h1[NM]; int w0[NM]; int w1[NM];   // written by k_top2p tail
};

// Find with plain-store path compression (ECL-CC). Safe concurrent with
// atomicMin linking: stored values are live ancestors; parent < child.
// Roots stay roots: L[x]==x returns early, never overwritten here.
__device__ __forceinline__ int find_c(int* L, int x) {
  int p = L[x];
  if (p == x) return x;
  int root = p, q = L[root];
  while (q != root) { root = q; q = L[root]; }
  if (root != p) L[x] = root;
  return root;
}

// Link larger root -> smaller root: final root = min id. Run/compact ids are
// assigned in pixel order of run starts, so min id == the reference's
// min-pixel-index component label.
__device__ void unite(int* L, int a, int b) {
  bool done = false;
  do {
    a = find_c(L, a);
    b = find_c(L, b);
    if (a < b)      { int old = atomicMin(&L[b], a); done = (old == b); b = old; }
    else if (b < a) { int old = atomicMin(&L[a], b); done = (old == a); a = old; }
    else done = true;
  } while (!done);
}

// Path-halving find (static tree; races only lose compression).
__device__ __forceinline__ int find_halve(int* L, int x) {
  int p = L[x];
  while (p != x) {
    int gp = L[p];
    if (gp == p) return p;
    L[x] = gp;
    x = p; p = gp;
  }
  return x;
}

__device__ __forceinline__ int cid(const unsigned long long* rm,
                                   const int* rpre, int r) {
  int w = r >> 6, b = r & 63;
  return rpre[w] + (int)__popcll(rm[w] & (b ? ((1ull << b) - 1) : 0ull));
}

__device__ __forceinline__ unsigned long long mask_le(int b) {  // bits 0..b
  return (b == 63) ? ~0ull : ((1ull << (b + 1)) - 1);
}
__device__ __forceinline__ unsigned long long mask_lt(int b) {  // bits 0..b-1
  return b ? ((1ull << b) - 1) : 0ull;
}

// One block = one 16x256 tile. Run-based LDS union-find; per-tile outputs are
// plain stores. Fused tail: the 16th (last-arriving) block of each mask runs
// that mask's 15 seam-row unions (formerly k_seam) — overlaps with the other
// masks' still-running blocks, deleting a launch without narrowing the work.
__global__ __launch_bounds__(512)
void k_local(const float* __restrict__ in, int cb,
             int* __restrict__ gp, int* __restrict__ ga,
             unsigned int* __restrict__ gbb, unsigned short* __restrict__ gl,
             unsigned short* __restrict__ gbrow, int* __restrict__ gnr,
             double* __restrict__ tdsum, unsigned int* __restrict__ tbb,
             int* __restrict__ gfg0, int* __restrict__ cntA) {
  __shared__ unsigned long long sfgw[TRR][4];   // fg row bitmasks
  __shared__ unsigned char sfgc[TRR][32];
  __shared__ unsigned long long srs[TRR][4];    // run-start bitmasks
  __shared__ int wpre64[64];   // global run-id base per (row,word)
  __shared__ int snr;          // total runs
  __shared__ int sspan[RMX];   // (row<<16)|(a<<8)|b
  __shared__ int suf[RMX];     // UF parent over run ids
  __shared__ unsigned long long rootm[32];      // root bitmask over run ids
  __shared__ int rpre[32];
  __shared__ int sA[SPT], sW0[SPT], sW1[SPT], sH0[SPT], sH1[SPT];  // 20 KB
  __shared__ double sred[8];
  __shared__ int sbb[4][8];
  __shared__ int slast;

  int q = blockIdx.x, lm = q >> 4, tile = q & 15;
  int tid = threadIdx.x, lane = tid & 63, wv = tid >> 6;
  int gm = cb + lm, R0 = tile << 4;

  // P1: load input (8 contiguous px/thread), m, dsum, fg bits — identical
  // order to prior rounds -> bit-identical dsum partials.
  int r1 = tid >> 5, cs = tid & 31;
  const float4* src =
      (const float4*)(in + ((size_t)gm << 16) + ((R0 + r1) << 8) + (cs << 3));
  double dsum = 0.0;
  unsigned int fgb = 0;
  for (int k = 0; k < 2; k++) {
    float4 v = src[k];
    float m0 = fmaxf((v.x + 1.0f) * 0.5f, 0.0f);
    float m1 = fmaxf((v.y + 1.0f) * 0.5f, 0.0f);
    float m2 = fmaxf((v.z + 1.0f) * 0.5f, 0.0f);
    float m3 = fmaxf((v.w + 1.0f) * 0.5f, 0.0f);
    dsum += (double)m0 + (double)m1 + (double)m2 + (double)m3;
    fgb |= ((m0 > 0.5f) ? 1u : 0u) << (4 * k);
    fgb |= ((m1 > 0.5f) ? 1u : 0u) << (4 * k + 1);
    fgb |= ((m2 > 0.5f) ? 1u : 0u) << (4 * k + 2);
    fgb |= ((m3 > 0.5f) ? 1u : 0u) << (4 * k + 3);
  }
  sfgc[r1][cs] = (unsigned char)fgb;
  __syncthreads();
  if (tid < 64) {   // 16 rows x 4 words
    int row = tid >> 2, w = tid & 3;
    const unsigned char* pc = &sfgc[row][w << 3];
    unsigned long long wd = 0;
    for (int i = 0; i < 8; i++) wd |= ((unsigned long long)pc[i]) << (i << 3);
    sfgw[row][w] = wd;
  }
  __syncthreads();

  // P2 (wave 0): run-start masks, global run ids via wave prefix, span
  // enumeration. Other waves zero the per-component stats arrays.
  if (tid < 64) {
    int row = tid >> 2, w = tid & 3;
    unsigned long long W = sfgw[row][w];
    unsigned long long carry = (w > 0) ? (sfgw[row][w - 1] >> 63) : 0ull;
    unsigned long long rs = W & ~((W << 1) | carry);
    srs[row][w] = rs;
    int cnt = (int)__popcll(rs);
    int sa = cnt;
    for (int off = 1; off < 64; off <<= 1) {
      int t = __shfl_up(sa, off);
      if (tid >= off) sa += t;
    }
    wpre64[tid] = sa - cnt;
    if (tid == 63) snr = sa;
    int id = sa - cnt;
    unsigned long long bits = rs;
    while (bits) {
      int a = (int)__ffsll(bits) - 1;
      bits &= bits - 1;
      int A = (w << 6) + a;
      unsigned long long inv = ~(W >> a);
      int len = inv ? ((int)__ffsll(inv) - 1) : (64 - a);
      if (len == 64 - a) {
        for (int w2 = w + 1; w2 < 4; w2++) {
          unsigned long long iv2 = ~sfgw[row][w2];
          int t = iv2 ? ((int)__ffsll(iv2) - 1) : 64;
          len += t;
          if (t < 64) break;
        }
      }
      sspan[id] = (row << 16) | (A << 8) | (A + len - 1);
      suf[id] = id;
      id++;
    }
  } else {
    for (int s = tid - 64; s < SPT; s += 448) {
      sA[s] = 0; sW0[s] = WW; sW1[s] = -1; sH0[s] = TRR; sH1[s] = -1;
    }
  }
  __syncthreads();

  int nr = snr;

  // P3: run-to-run unions via windowed overlap with the previous row.
  for (int i = tid; i < nr; i += 512) {
    int sp = sspan[i];
    int row = sp >> 16, a = (sp >> 8) & 255, b = sp & 255;
    if (row == 0) continue;
    int lo = max(a - 1, 0), hi = min(b + 1, 255);
    const unsigned long long* Wp = sfgw[row - 1];
    const unsigned long long* Rp = srs[row - 1];
    int prebase = (row - 1) << 2;
    int lw = lo >> 6, lb = lo & 63;
    if (((Wp[lw] >> lb) & 1) && !((Rp[lw] >> lb) & 1)) {
      int j = wpre64[prebase + lw] + (int)__popcll(Rp[lw] & mask_le(lb)) - 1;
      unite(suf, i, j);
    }
    for (int w = lw; w <= (hi >> 6); w++) {
      unsigned long long m = Rp[w];
      if (w == lw) m &= ~mask_lt(lb);
      if (w == (hi >> 6)) m &= mask_le(hi & 63);
      int base2 = wpre64[prebase + w];
      while (m) {
        int bb = (int)__ffsll(m) - 1;
        m &= m - 1;
        int j = base2 + (int)__popcll(Rp[w] & mask_lt(bb));
        unite(suf, i, j);
      }
    }
  }
  __syncthreads();

  // P4: root bitmask over run ids (parent==self ballot), compact prefix.
  for (int j = 0; j < 4; j++) {
    int i = tid + (j << 9);
    unsigned long long bal = __ballot(i < nr && suf[i] == i);
    if (lane == 0) rootm[wv + (j << 3)] = bal;
  }
  __syncthreads();
  if (tid < 32) {
    int pc = (int)__popcll(rootm[tid]);
    int sa = pc;
    for (int off = 1; off < 32; off <<= 1) {
      int t = __shfl_up(sa, off);
      if (tid >= off) sa += t;
    }
    rpre[tid] = sa - pc;
  }
  __syncthreads();

  // P5: per-run stats (direct atomics — wave-aggregation loses here, ~40
  // distinct components per wave; measured R11/R12).
  for (int i = tid; i < nr; i += 512) {
    int root = find_halve(suf, i);
    int id = cid(rootm, rpre, root);
    int sp = sspan[i];
    int row = sp >> 16, a = (sp >> 8) & 255, b = sp & 255;
    atomicAdd(&sA[id], b - a + 1);
    if (a < sW0[id]) atomicMin(&sW0[id], a);
    if (b > sW1[id]) atomicMax(&sW1[id], b);
    if (row < sH0[id]) atomicMin(&sH0[id], row);
    if (row > sH1[id]) atomicMax(&sH1[id], row);
  }
  __syncthreads();

  // P6a: emit compact root records.
  int nc = rpre[31] + (int)__popcll(rootm[31]);
  for (int i = tid; i < nr; i += 512) {
    if (suf[i] == i) {
      int id = cid(rootm, rpre, i);
      int gid = (lm << 14) + (tile << 10) + id;
      int sp = sspan[i];
      gp[gid] = gid;
      ga[gid] = sA[id];
      gl[gid] = (unsigned short)((tile << 12) + ((sp >> 16) << 8) +
                                 ((sp >> 8) & 255));
      gbb[gid] = ((unsigned)(R0 + sH0[id]) << 24) | ((unsigned)sW0[id] << 16)
               | ((unsigned)(R0 + sH1[id]) << 8) | (unsigned)sW1[id];
    }
  }
  // P6b: boundary maps (1 boundary px/thread: 2 rows x 256 cols).
  {
    int c = tid & 255, topbot = tid >> 8;
    int brow = topbot ? (TRR - 1) : 0;
    unsigned short val = 0xFFFF;
    if ((sfgw[brow][c >> 6] >> (c & 63)) & 1) {
      int w = c >> 6, bb = c & 63;
      int id = wpre64[(brow << 2) + w] +
               (int)__popcll(srs[brow][w] & mask_le(bb)) - 1;
      int root = find_halve(suf, id);
      val = (unsigned short)((tile << 10) + cid(rootm, rpre, root));
    }
    gbrow[(q << 9) + (topbot ? 256 : 0) + c] = val;
  }
  if (tid == 0) gnr[q] = nc;

  // P7: bg bbox + dsum reductions; plain-store per-tile records.
  int c = tid & 255, half = (tid >> 8) << 3;
  int bh0r = TRR, bh1r = -1;
  bool anybg = false;
  for (int row = half; row < half + 8; row++) {
    if (!((sfgw[row][c >> 6] >> (c & 63)) & 1)) {
      anybg = true;
      bh0r = min(bh0r, row); bh1r = max(bh1r, row);
    }
  }
  int bw0r = anybg ? c : WW, bw1r = anybg ? c : -1;
  for (int off = 32; off > 0; off >>= 1) {
    bw0r = min(bw0r, __shfl_down(bw0r, off));
    bw1r = max(bw1r, __shfl_down(bw1r, off));
    bh0r = min(bh0r, __shfl_down(bh0r, off));
    bh1r = max(bh1r, __shfl_down(bh1r, off));
  }
  if (lane == 0) { sbb[0][wv] = bw0r; sbb[1][wv] = bw1r;
                   sbb[2][wv] = bh0r; sbb[3][wv] = bh1r; }
  for (int off = 32; off > 0; off >>= 1) dsum += __shfl_down(dsum, off);
  if (lane == 0) sred[wv] = dsum;
  __syncthreads();
  if (tid == 0) {
    int a0 = sbb[0][0], a1 = sbb[1][0], a2 = sbb[2][0], a3 = sbb[3][0];
    for (int i = 1; i < 8; i++) {
      a0 = min(a0, sbb[0][i]); a1 = max(a1, sbb[1][i]);
      a2 = min(a2, sbb[2][i]); a3 = max(a3, sbb[3][i]);
    }
    unsigned pack = (a1 >= 0)
        ? (((unsigned)(R0 + a2) << 24) | ((unsigned)a0 << 16) |
           ((unsigned)(R0 + a3) << 8) | (unsigned)a1)
        : 0xFFFF0000u;
    tbb[q] = pack;
    double t = 0.0;
    for (int i = 0; i < 8; i++) t += sred[i];
    tdsum[q] = t;
    if (tile == 0) gfg0[lm] = (int)(sfgw[0][0] & 1ull);
  }

  // P8: last-arriver seam unions (fused k_seam). Release: every thread
  // fences its own global writes, then block syncs, then tid0 publishes.
  __threadfence();
  __syncthreads();
  if (tid == 0) slast = (atomicAdd(&cntA[gm], 1) == 15) ? 1 : 0;
  __syncthreads();
  if (slast) {
    __threadfence();   // acquire: see peer tiles' gbrow/gp
    int sbase = lm << 14;
    for (int idx = tid; idx < 15 * 256; idx += 512) {
      int s = idx >> 8, c2 = idx & 255;
      const unsigned short* up = gbrow + (((lm << 4) + s) << 9) + 256;
      const unsigned short* lo = gbrow + (((lm << 4) + s + 1) << 9);
      unsigned short v16 = lo[c2];
      if (v16 == 0xFFFF) continue;
      int v = sbase + v16;
      bool wfg = (c2 > 0) && (lo[c2 - 1] != 0xFFFF);
      unsigned short n16 = up[c2];
      if (!wfg) {
        if (n16 != 0xFFFF) unite(gp, v, sbase + n16);
        else if (c2 > 0 && up[c2 - 1] != 0xFFFF)
          unite(gp, v, sbase + up[c2 - 1]);
      }
      if (n16 == 0xFFFF && c2 < 255 && up[c2 + 1] != 0xFFFF)
        unite(gp, v, sbase + up[c2 + 1]);
    }
  }
}

// Wide push (cn*16): per distinct final root per wave, ONE atomicAdd for the
// area and ONE CAS-merge of the packed bbox into gbb[root].
__global__ void k_push(int* __restrict__ gp, int* __restrict__ ga,
                       unsigned int* __restrict__ gbb,
                       const int* __restrict__ gnr) {
  int q = blockIdx.x;
  int lm = q >> 4;
  int sbase = lm << 14;
  int nc = gnr[q];
  int tid = threadIdx.x, lane = tid & 63;
  for (int t = 0; t < 4; t++) {
    int slot = (t << 8) + tid;
    int r = -1, a = 0;
    int h0 = HH, w0 = WW, h1 = -1, w1 = -1;
    if (slot < nc) {
      int gid = sbase + ((q & 15) << 10) + slot;
      int rr = find_c(gp, gid);
      if (rr != gid) {
        r = rr; a = ga[gid];
        unsigned int bb = gbb[gid];
        h0 = (int)(bb >> 24); w0 = (int)((bb >> 16) & 255);
        h1 = (int)((bb >> 8) & 255); w1 = (int)(bb & 255);
      }
    }
    bool pend = (r >= 0);
    while (__any(pend)) {
      unsigned long long mk = __ballot(pend);
      int srcl = (int)__ffsll(mk) - 1;
      int lead = __shfl(r, srcl);
      bool mine = pend && (r == lead);
      int v  = mine ? a  : 0;
      int g0 = mine ? h0 : HH;
      int g1 = mine ? h1 : -1;
      int g2 = mine ? w0 : WW;
      int g3 = mine ? w1 : -1;
      for (int off = 32; off > 0; off >>= 1) {
        v += __shfl_down(v, off);
        g0 = min(g0, __shfl_down(g0, off));
        g1 = max(g1, __shfl_down(g1, off));
        g2 = min(g2, __shfl_down(g2, off));
        g3 = max(g3, __shfl_down(g3, off));
      }
      int tot = __shfl(v, 0);
      int m0 = __shfl(g0, 0), m1 = __shfl(g1, 0);
      int m2 = __shfl(g2, 0), m3 = __shfl(g3, 0);
      if (lane == srcl) {
        atomicAdd(&ga[lead], tot);
        unsigned int* dst = &gbb[lead];
        unsigned int old = *dst;
        while (true) {
          int oh0 = (int)(old >> 24), ow0 = (int)((old >> 16) & 255);
          int oh1 = (int)((old >> 8) & 255), ow1 = (int)(old & 255);
          int nh0 = min(oh0, m0), nw0 = min(ow0, m2);
          int nh1 = max(oh1, m1), nw1 = max(ow1, m3);
          unsigned int mrg = ((unsigned)nh0 << 24) | ((unsigned)nw0 << 16) |
                             ((unsigned)nh1 << 8) | (unsigned)nw1;
          if (mrg == old) break;
          unsigned int got = atomicCAS(dst, old, mrg);
          if (got == old) break;
          old = got;
        }
      }
      pend = pend && !mine;
    }
  }
}

// Wide per-tile top-2 partials (cn*16) + fused k_mask tail: the 16th block of
// each mask reduces the 16 tile records and writes mt (bbox from gbb[secgid],
// fully merged by k_push).
// key = (area<<37)|((SS-lab)<<20)|slot : (area desc, label asc).
__global__ void k_top2p(const int* __restrict__ gp, const int* __restrict__ ga,
                        const unsigned short* __restrict__ gl,
                        const int* __restrict__ gnr,
                        unsigned long long* __restrict__ tt1,
                        unsigned long long* __restrict__ tt2,
                        int* __restrict__ tfs,
                        const double* __restrict__ tdsum,
                        const unsigned int* __restrict__ tbb,
                        const int* __restrict__ gfg0,
                        const unsigned int* __restrict__ gbb,
                        int* __restrict__ cntB,
                        Meta* __restrict__ mt, int c0) {
  int q = blockIdx.x;
  int lm = q >> 4, tile = q & 15;
  int gm = c0 + lm;
  int sbase = lm << 14;
  int nc = gnr[q];
  int tid = threadIdx.x, lane = tid & 63, wv = tid >> 6;
  __shared__ int slast;
  unsigned long long t1 = 0, t2 = 0;
  int fsum = 0;
  for (int sl = tid; sl < nc; sl += 256) {
    int s = (tile << 10) + sl;
    int gid = sbase + s;
    if (gp[gid] == gid) {
      int a = ga[gid];
      int lab = gl[gid];
      fsum += a;
      unsigned long long key = ((unsigned long long)a << 37)
                             | ((unsigned long long)(SS - lab) << 20)
                             | (unsigned)s;
      if (key > t1) { t2 = t1; t1 = key; }
      else if (key > t2) t2 = key;
    }
  }
  for (int off = 32; off > 0; off >>= 1) {
    unsigned long long o1 = __shfl_down(t1, off), o2 = __shfl_down(t2, off);
    if (o1 > t1) { t2 = (t1 > o2) ? t1 : o2; t1 = o1; }
    else if (o1 > t2) t2 = o1;
    fsum += __shfl_down(fsum, off);
  }
  __shared__ unsigned long long s1[4], s2[4];
  __shared__ int sf[4];
  if (lane == 0) { s1[wv] = t1; s2[wv] = t2; sf[wv] = fsum; }
  __syncthreads();
  if (tid == 0) {
    for (int i = 1; i < 4; i++) {
      unsigned long long o1 = s1[i], o2 = s2[i];
      if (o1 > t1) { t2 = (t1 > o2) ? t1 : o2; t1 = o1; }
      else if (o1 > t2) t2 = o1;
      fsum += sf[i];
    }
    tt1[q] = t1; tt2[q] = t2; tfs[q] = fsum;
  }

  // Fused k_mask: last arriver's wave 0 does the per-mask finish.
  __threadfence();
  __syncthreads();
  if (tid == 0) slast = (atomicAdd(&cntB[gm], 1) == 15) ? 1 : 0;
  __syncthreads();
  if (slast && wv == 0) {
    __threadfence();   // acquire: see peer tiles' tt1/tt2/tfs
    int tb = lm << 4;
    double d = 0.0;
    int h0 = 255, w0 = 255, h1 = 0, w1 = 0;
    unsigned long long u1 = 0, u2 = 0;
    int fs = 0;
    if (lane < 16) {
      d = tdsum[tb + lane];
      unsigned bb = tbb[tb + lane];
      h0 = (int)(bb >> 24); w0 = (int)((bb >> 16) & 255);
      h1 = (int)((bb >> 8) & 255); w1 = (int)(bb & 255);
      u1 = tt1[tb + lane]; u2 = tt2[tb + lane]; fs = tfs[tb + lane];
    }
    for (int off = 8; off > 0; off >>= 1) {
      d += __shfl_down(d, off);
      h0 = min(h0, __shfl_down(h0, off));
      w0 = min(w0, __shfl_down(w0, off));
      h1 = max(h1, __shfl_down(h1, off));
      w1 = max(w1, __shfl_down(w1, off));
      unsigned long long o1 = __shfl_down(u1, off), o2 = __shfl_down(u2, off);
      if (o1 > u1) { u2 = (u1 > o2) ? u1 : o2; u1 = o1; }
      else if (o1 > u2) u2 = o1;
      fs += __shfl_down(fs, off);
    }
    if (lane == 0) {
      mt->dsum[gm] = d;
      unsigned long long bg = ((unsigned long long)(SS - fs)) << 37;
      int zl = gfg0[lm] ? 1 : 0;   // best zero-area label (R5/R7 proof)
      unsigned long long zk = ((unsigned long long)(SS - zl)) << 20;
      if (bg > u1) { u2 = u1; u1 = bg; } else if (bg > u2) u2 = bg;
      if (zk > u1) { u2 = u1; u1 = zk; } else if (zk > u2) u2 = zk;
      if (u2 == bg) {
        mt->h0[gm] = h0; mt->h1[gm] = h1; mt->w0[gm] = w0; mt->w1[gm] = w1;
      } else if (u2 == zk) {
        mt->h0[gm] = 1; mt->h1[gm] = 0; mt->w0[gm] = 1; mt->w1[gm] = 0;
      } else {
        unsigned int bb = gbb[(lm << 14) + (int)(u2 & 0xFFFFF)];
        mt->h0[gm] = (int)(bb >> 24);
        mt->w0[gm] = (int)((bb >> 16) & 255);
        mt->h1[gm] = (int)((bb >> 8) & 255);
        mt->w1[gm] = (int)(bb & 255);
      }
    }
  }
}

// 8 blocks per mask over the bbox rows; plain-store per-seg double partials.
// Fused k_final on the last chunk: last arriving block reduces all masks.
__global__ void k_inside(const float* __restrict__ in,
                         const Meta* __restrict__ mt,
                         double* __restrict__ dinsp, int c0,
                         int* __restrict__ cntC, int nb, int do_final,
                         float* __restrict__ out) {
  int b = blockIdx.x;
  int lm = b >> 3, seg = b & 7;
  int gm = c0 + lm;
  int h0 = mt->h0[gm], h1 = mt->h1[gm], w0 = mt->w0[gm], w1 = mt->w1[gm];
  double acc = 0.0;
  if (h1 >= h0) {
    int cc = w0 + threadIdx.x;
    if (cc <= w1) {
      const float* base = in + ((size_t)gm << 16);
      for (int rr = h0 + seg; rr <= h1; rr += 8) {
        float x = base[(rr << 8) + cc];
        acc += (double)fmaxf((x + 1.0f) * 0.5f, 0.0f);
      }
    }
  }
  for (int off = 32; off > 0; off >>= 1) acc += __shfl_down(acc, off);
  __shared__ double sd[4];
  int wid = threadIdx.x >> 6, lane = threadIdx.x & 63;
  if (lane == 0) sd[wid] = acc;
  __syncthreads();
  if (threadIdx.x == 0)
    dinsp[(gm << 3) + seg] = sd[0] + sd[1] + sd[2] + sd[3];

  if (do_final) {
    __shared__ int sflag;
    if (threadIdx.x == 0) {
      __threadfence();   // release this block's dinsp store
      sflag = (atomicAdd(cntC, 1) == nb - 1) ? 1 : 0;
    }
    __syncthreads();
    if (sflag) {
      __threadfence();   // acquire peers' dinsp (earlier chunks: launch order)
      __shared__ double sd2[NM];
      int t = threadIdx.x;
      if (t < NM) {
        double di = 0.0;
        for (int s = 0; s < 8; s++) di += dinsp[(t << 3) + s];
        sd2[t] = (mt->dsum[t] - di) / (double)SS;
      }
      __syncthreads();
      for (int off = 64; off > 0; off >>= 1) {
        if (t < off) sd2[t] += sd2[t + off];
        __syncthreads();
      }
      if (t == 0) out[0] = (float)(sd2[0] / (double)NM);
    }
  }
}

extern "C" void kernel_launch(void* const* d_in, const int* in_sizes, int n_in,
                              void* d_out, int out_size, void* d_ws,
                              size_t ws_size, hipStream_t stream) {
  const float* in = (const float*)d_in[0];
  float* out = (float*)d_out;

  Meta* mt = (Meta*)d_ws;
  const size_t meta_bytes = (sizeof(Meta) + 255) & ~(size_t)255;
  char* base = (char*)d_ws + meta_bytes;
  // fixed region: dinsp (NM*8 doubles) + counters cntA[NM], cntB[NM], cntC[1]
  const size_t cnt_bytes = ((size_t)(NM * 2 + 1) * 4 + 255) & ~(size_t)255;
  size_t fixed = (size_t)NM * 8 * sizeof(double) + cnt_bytes;
  size_t avail = (ws_size > meta_bytes + fixed)
                     ? (ws_size - meta_bytes - fixed) : 0;
  const size_t per_mask = (size_t)NT2 * 8 + NT2 * 4 + 4 +
                          (size_t)SPM * (4 + 4 + 4 + 2) +
                          (size_t)NT2 * 512 * 2 + NT2 * 4 +
                          (size_t)NT2 * (8 + 8 + 4);   // tt1,tt2,tfs
  int chunk = (int)(avail / per_mask);
  if (chunk > NM) chunk = NM;
  if (chunk < 1) return;  // insufficient workspace (would fail validation)

  char* ptr = base;
  double* dinsp = (double*)ptr;        ptr += (size_t)NM * 8 * 8;
  int* cntA = (int*)ptr;               // cntA[NM], cntB[NM], cntC[1]
  int* cntB = cntA + NM;
  int* cntC = cntB + NM;
  ptr += cnt_bytes;
  double* tdsum = (double*)ptr;        ptr += (size_t)chunk * NT2 * 8;
  unsigned long long* tt1 = (unsigned long long*)ptr;
  ptr += (size_t)chunk * NT2 * 8;
  unsigned long long* tt2 = (unsigned long long*)ptr;
  ptr += (size_t)chunk * NT2 * 8;
  int* gp = (int*)ptr;                 ptr += (size_t)chunk * SPM * 4;
  int* ga = (int*)ptr;                 ptr += (size_t)chunk * SPM * 4;
  unsigned int* gbb = (unsigned int*)ptr;       ptr += (size_t)chunk * SPM * 4;
  unsigned short* gl = (unsigned short*)ptr;    ptr += (size_t)chunk * SPM * 2;
  unsigned short* gbrow = (unsigned short*)ptr; ptr += (size_t)chunk * NT2 * 512 * 2;
  int* gnr = (int*)ptr;                ptr += (size_t)chunk * NT2 * 4;
  unsigned int* tbb = (unsigned int*)ptr;       ptr += (size_t)chunk * NT2 * 4;
  int* tfs = (int*)ptr;                ptr += (size_t)chunk * NT2 * 4;
  int* gfg0 = (int*)ptr;

  hipMemsetAsync(cntA, 0, (size_t)(NM * 2 + 1) * 4, stream);

  for (int c0 = 0; c0 < NM; c0 += chunk) {
    int cn = (chunk < NM - c0) ? chunk : (NM - c0);
    int do_final = (c0 + cn >= NM) ? 1 : 0;
    k_local<<<cn * NT2, 512, 0, stream>>>(in, c0, gp, ga, gbb, gl, gbrow,
                                          gnr, tdsum, tbb, gfg0, cntA);
    k_push <<<cn * NT2, 256, 0, stream>>>(gp, ga, gbb, gnr);
    k_top2p<<<cn * NT2, 256, 0, stream>>>(gp, ga, gl, gnr, tt1, tt2, tfs,
                                          tdsum, tbb, gfg0, gbb, cntB, mt,
                                          c0);
    k_inside<<<cn * 8, 256, 0, stream>>>(in, mt, dinsp, c0, cntC, cn * 8,
                                         do_final, out);
  }
}

// Round 17
// 184.387 us; speedup vs baseline: 3.8740x; 3.8740x over previous
//
#include <hip/hip_runtime.h>

#define HH 256
#define WW 256
#define SS 65536   // pixels per mask; also the background sentinel label
#define NM 128     // B*K masks
#define TRR 16     // rows per tile
#define NT2 16     // tiles per mask
#define RMX 2048   // max horizontal runs in a 16x256 tile
#define SPT 1024   // max 8-conn components in a 16x256 tile
#define SPM 16384  // slots per mask (16 tiles x 1024)

// All Meta fields are written (plain stores) before any consumer reads them
// -> no init kernel despite 0xAA poison.
struct Meta {
  double dsum[NM];                                  // written by k_mask
  int h0[NM]; int h1[NM]; int w0[NM]; int w1[NM];   // written by k_mask
};

// Find with plain-store path compression (ECL-CC). Safe concurrent with
// atomicMin linking: stored values are live ancestors; parent < child.
// Roots stay roots: L[x]==x returns early, never overwritten here.
__device__ __forceinline__ int find_c(int* L, int x) {
  int p = L[x];
  if (p == x) return x;
  int root = p, q = L[root];
  while (q != root) { root = q; q = L[root]; }
  if (root != p) L[x] = root;
  return root;
}

// Link larger root -> smaller root: final root = min id. Run/compact ids are
// assigned in pixel order of run starts, so min id == the reference's
// min-pixel-index component label.
__device__ void unite(int* L, int a, int b) {
  bool done = false;
  do {
    a = find_c(L, a);
    b = find_c(L, b);
    if (a < b)      { int old = atomicMin(&L[b], a); done = (old == b); b = old; }
    else if (b < a) { int old = atomicMin(&L[a], b); done = (old == a); a = old; }
    else done = true;
  } while (!done);
}

// Path-halving find (static tree; races only lose compression).
__device__ __forceinline__ int find_halve(int* L, int x) {
  int p = L[x];
  while (p != x) {
    int gp = L[p];
    if (gp == p) return p;
    L[x] = gp;
    x = p; p = gp;
  }
  return x;
}

__device__ __forceinline__ int cid(const unsigned long long* rm,
                                   const int* rpre, int r) {
  int w = r >> 6, b = r & 63;
  return rpre[w] + (int)__popcll(rm[w] & (b ? ((1ull << b) - 1) : 0ull));
}

__device__ __forceinline__ unsigned long long mask_le(int b) {  // bits 0..b
  return (b == 63) ? ~0ull : ((1ull << (b + 1)) - 1);
}
__device__ __forceinline__ unsigned long long mask_lt(int b) {  // bits 0..b-1
  return b ? ((1ull << b) - 1) : 0ull;
}

// One block = one 16x256 tile. Run-based LDS union-find; per-tile outputs are
// plain stores (no global atomics at all in this kernel). [frozen since R13]
// NOTE (R16): do NOT fuse cross-block tails into this kernel with
// __threadfence — mass device-scope fences on gfx950 (non-coherent per-XCD
// L2s) cost 8x total runtime (measured R15: 185 -> 714 µs).
__global__ __launch_bounds__(512)
void k_local(const float* __restrict__ in, int cb,
             int* __restrict__ gp, int* __restrict__ ga,
             unsigned int* __restrict__ gbb, unsigned short* __restrict__ gl,
             unsigned short* __restrict__ gbrow, int* __restrict__ gnr,
             double* __restrict__ tdsum, unsigned int* __restrict__ tbb,
             int* __restrict__ gfg0) {
  __shared__ unsigned long long sfgw[TRR][4];   // fg row bitmasks
  __shared__ unsigned char sfgc[TRR][32];
  __shared__ unsigned long long srs[TRR][4];    // run-start bitmasks
  __shared__ int wpre64[64];   // global run-id base per (row,word)
  __shared__ int snr;          // total runs
  __shared__ int sspan[RMX];   // (row<<16)|(a<<8)|b
  __shared__ int suf[RMX];     // UF parent over run ids
  __shared__ unsigned long long rootm[32];      // root bitmask over run ids
  __shared__ int rpre[32];
  __shared__ int sA[SPT], sW0[SPT], sW1[SPT], sH0[SPT], sH1[SPT];  // 20 KB
  __shared__ double sred[8];
  __shared__ int sbb[4][8];

  int q = blockIdx.x, lm = q >> 4, tile = q & 15;
  int tid = threadIdx.x, lane = tid & 63, wv = tid >> 6;
  int gm = cb + lm, R0 = tile << 4;

  // P1: load input (8 contiguous px/thread), m, dsum, fg bits — identical
  // order to prior rounds -> bit-identical dsum partials.
  int r1 = tid >> 5, cs = tid & 31;
  const float4* src =
      (const float4*)(in + ((size_t)gm << 16) + ((R0 + r1) << 8) + (cs << 3));
  double dsum = 0.0;
  unsigned int fgb = 0;
  for (int k = 0; k < 2; k++) {
    float4 v = src[k];
    float m0 = fmaxf((v.x + 1.0f) * 0.5f, 0.0f);
    float m1 = fmaxf((v.y + 1.0f) * 0.5f, 0.0f);
    float m2 = fmaxf((v.z + 1.0f) * 0.5f, 0.0f);
    float m3 = fmaxf((v.w + 1.0f) * 0.5f, 0.0f);
    dsum += (double)m0 + (double)m1 + (double)m2 + (double)m3;
    fgb |= ((m0 > 0.5f) ? 1u : 0u) << (4 * k);
    fgb |= ((m1 > 0.5f) ? 1u : 0u) << (4 * k + 1);
    fgb |= ((m2 > 0.5f) ? 1u : 0u) << (4 * k + 2);
    fgb |= ((m3 > 0.5f) ? 1u : 0u) << (4 * k + 3);
  }
  sfgc[r1][cs] = (unsigned char)fgb;
  __syncthreads();
  if (tid < 64) {   // 16 rows x 4 words
    int row = tid >> 2, w = tid & 3;
    const unsigned char* pc = &sfgc[row][w << 3];
    unsigned long long wd = 0;
    for (int i = 0; i < 8; i++) wd |= ((unsigned long long)pc[i]) << (i << 3);
    sfgw[row][w] = wd;
  }
  __syncthreads();

  // P2 (wave 0): run-start masks, global run ids via wave prefix, span
  // enumeration. Other waves zero the per-component stats arrays.
  if (tid < 64) {
    int row = tid >> 2, w = tid & 3;
    unsigned long long W = sfgw[row][w];
    unsigned long long carry = (w > 0) ? (sfgw[row][w - 1] >> 63) : 0ull;
    unsigned long long rs = W & ~((W << 1) | carry);
    srs[row][w] = rs;
    int cnt = (int)__popcll(rs);
    int sa = cnt;
    for (int off = 1; off < 64; off <<= 1) {
      int t = __shfl_up(sa, off);
      if (tid >= off) sa += t;
    }
    wpre64[tid] = sa - cnt;
    if (tid == 63) snr = sa;
    int id = sa - cnt;
    unsigned long long bits = rs;
    while (bits) {
      int a = (int)__ffsll(bits) - 1;
      bits &= bits - 1;
      int A = (w << 6) + a;
      unsigned long long inv = ~(W >> a);
      int len = inv ? ((int)__ffsll(inv) - 1) : (64 - a);
      if (len == 64 - a) {
        for (int w2 = w + 1; w2 < 4; w2++) {
          unsigned long long iv2 = ~sfgw[row][w2];
          int t = iv2 ? ((int)__ffsll(iv2) - 1) : 64;
          len += t;
          if (t < 64) break;
        }
      }
      sspan[id] = (row << 16) | (A << 8) | (A + len - 1);
      suf[id] = id;
      id++;
    }
  } else {
    for (int s = tid - 64; s < SPT; s += 448) {
      sA[s] = 0; sW0[s] = WW; sW1[s] = -1; sH0[s] = TRR; sH1[s] = -1;
    }
  }
  __syncthreads();

  int nr = snr;

  // P3: run-to-run unions via windowed overlap with the previous row.
  for (int i = tid; i < nr; i += 512) {
    int sp = sspan[i];
    int row = sp >> 16, a = (sp >> 8) & 255, b = sp & 255;
    if (row == 0) continue;
    int lo = max(a - 1, 0), hi = min(b + 1, 255);
    const unsigned long long* Wp = sfgw[row - 1];
    const unsigned long long* Rp = srs[row - 1];
    int prebase = (row - 1) << 2;
    int lw = lo >> 6, lb = lo & 63;
    if (((Wp[lw] >> lb) & 1) && !((Rp[lw] >> lb) & 1)) {
      int j = wpre64[prebase + lw] + (int)__popcll(Rp[lw] & mask_le(lb)) - 1;
      unite(suf, i, j);
    }
    for (int w = lw; w <= (hi >> 6); w++) {
      unsigned long long m = Rp[w];
      if (w == lw) m &= ~mask_lt(lb);
      if (w == (hi >> 6)) m &= mask_le(hi & 63);
      int base2 = wpre64[prebase + w];
      while (m) {
        int bb = (int)__ffsll(m) - 1;
        m &= m - 1;
        int j = base2 + (int)__popcll(Rp[w] & mask_lt(bb));
        unite(suf, i, j);
      }
    }
  }
  __syncthreads();

  // P4: root bitmask over run ids (parent==self ballot), compact prefix.
  for (int j = 0; j < 4; j++) {
    int i = tid + (j << 9);
    unsigned long long bal = __ballot(i < nr && suf[i] == i);
    if (lane == 0) rootm[wv + (j << 3)] = bal;
  }
  __syncthreads();
  if (tid < 32) {
    int pc = (int)__popcll(rootm[tid]);
    int sa = pc;
    for (int off = 1; off < 32; off <<= 1) {
      int t = __shfl_up(sa, off);
      if (tid >= off) sa += t;
    }
    rpre[tid] = sa - pc;
  }
  __syncthreads();

  // P5: per-run stats (direct atomics — wave-aggregation loses here, ~40
  // distinct components per wave; measured R11/R12).
  for (int i = tid; i < nr; i += 512) {
    int root = find_halve(suf, i);
    int id = cid(rootm, rpre, root);
    int sp = sspan[i];
    int row = sp >> 16, a = (sp >> 8) & 255, b = sp & 255;
    atomicAdd(&sA[id], b - a + 1);
    if (a < sW0[id]) atomicMin(&sW0[id], a);
    if (b > sW1[id]) atomicMax(&sW1[id], b);
    if (row < sH0[id]) atomicMin(&sH0[id], row);
    if (row > sH1[id]) atomicMax(&sH1[id], row);
  }
  __syncthreads();

  // P6a: emit compact root records.
  int nc = rpre[31] + (int)__popcll(rootm[31]);
  for (int i = tid; i < nr; i += 512) {
    if (suf[i] == i) {
      int id = cid(rootm, rpre, i);
      int gid = (lm << 14) + (tile << 10) + id;
      int sp = sspan[i];
      gp[gid] = gid;
      ga[gid] = sA[id];
      gl[gid] = (unsigned short)((tile << 12) + ((sp >> 16) << 8) +
                                 ((sp >> 8) & 255));
      gbb[gid] = ((unsigned)(R0 + sH0[id]) << 24) | ((unsigned)sW0[id] << 16)
               | ((unsigned)(R0 + sH1[id]) << 8) | (unsigned)sW1[id];
    }
  }
  // P6b: boundary maps (1 boundary px/thread: 2 rows x 256 cols).
  {
    int c = tid & 255, topbot = tid >> 8;
    int brow = topbot ? (TRR - 1) : 0;
    unsigned short val = 0xFFFF;
    if ((sfgw[brow][c >> 6] >> (c & 63)) & 1) {
      int w = c >> 6, bb = c & 63;
      int id = wpre64[(brow << 2) + w] +
               (int)__popcll(srs[brow][w] & mask_le(bb)) - 1;
      int root = find_halve(suf, id);
      val = (unsigned short)((tile << 10) + cid(rootm, rpre, root));
    }
    gbrow[(q << 9) + (topbot ? 256 : 0) + c] = val;
  }
  if (tid == 0) gnr[q] = nc;

  // P7: bg bbox + dsum reductions; plain-store per-tile records.
  int c = tid & 255, half = (tid >> 8) << 3;
  int bh0r = TRR, bh1r = -1;
  bool anybg = false;
  for (int row = half; row < half + 8; row++) {
    if (!((sfgw[row][c >> 6] >> (c & 63)) & 1)) {
      anybg = true;
      bh0r = min(bh0r, row); bh1r = max(bh1r, row);
    }
  }
  int bw0r = anybg ? c : WW, bw1r = anybg ? c : -1;
  for (int off = 32; off > 0; off >>= 1) {
    bw0r = min(bw0r, __shfl_down(bw0r, off));
    bw1r = max(bw1r, __shfl_down(bw1r, off));
    bh0r = min(bh0r, __shfl_down(bh0r, off));
    bh1r = max(bh1r, __shfl_down(bh1r, off));
  }
  if (lane == 0) { sbb[0][wv] = bw0r; sbb[1][wv] = bw1r;
                   sbb[2][wv] = bh0r; sbb[3][wv] = bh1r; }
  for (int off = 32; off > 0; off >>= 1) dsum += __shfl_down(dsum, off);
  if (lane == 0) sred[wv] = dsum;
  __syncthreads();
  if (tid == 0) {
    int a0 = sbb[0][0], a1 = sbb[1][0], a2 = sbb[2][0], a3 = sbb[3][0];
    for (int i = 1; i < 8; i++) {
      a0 = min(a0, sbb[0][i]); a1 = max(a1, sbb[1][i]);
      a2 = min(a2, sbb[2][i]); a3 = max(a3, sbb[3][i]);
    }
    unsigned pack = (a1 >= 0)
        ? (((unsigned)(R0 + a2) << 24) | ((unsigned)a0 << 16) |
           ((unsigned)(R0 + a3) << 8) | (unsigned)a1)
        : 0xFFFF0000u;
    tbb[q] = pack;
    double t = 0.0;
    for (int i = 0; i < 8; i++) t += sred[i];
    tdsum[q] = t;
    if (tile == 0) gfg0[lm] = (int)(sfgw[0][0] & 1ull);
  }
}

// Wide seam unions (cn*15 blocks) — narrow launches of global UF regress
// ~25 µs (measured R11); in-kernel fence fusion regresses 8x (measured R15).
__global__ void k_seam(int* __restrict__ gp,
                       const unsigned short* __restrict__ gbrow) {
  int b = blockIdx.x;
  int lm = b / 15, s = b % 15;
  int tb = lm << 4;
  int sbase = lm << 14;
  const unsigned short* up = gbrow + ((tb + s) << 9) + 256;
  const unsigned short* lo = gbrow + ((tb + s + 1) << 9);
  int c = threadIdx.x;
  unsigned short v16 = lo[c];
  if (v16 == 0xFFFF) return;
  int v = sbase + v16;
  bool wfg = (c > 0) && (lo[c - 1] != 0xFFFF);
  unsigned short n16 = up[c];
  if (!wfg) {
    if (n16 != 0xFFFF) unite(gp, v, sbase + n16);
    else if (c > 0 && up[c - 1] != 0xFFFF) unite(gp, v, sbase + up[c - 1]);
  }
  if (n16 == 0xFFFF && c < 255 && up[c + 1] != 0xFFFF)
    unite(gp, v, sbase + up[c + 1]);
}

// Wide push (cn*16): per distinct final root per wave, ONE atomicAdd for the
// area and ONE CAS-merge of the packed bbox into gbb[root].
__global__ void k_push(int* __restrict__ gp, int* __restrict__ ga,
                       unsigned int* __restrict__ gbb,
                       const int* __restrict__ gnr) {
  int q = blockIdx.x;
  int lm = q >> 4;
  int sbase = lm << 14;
  int nc = gnr[q];
  int tid = threadIdx.x, lane = tid & 63;
  for (int t = 0; t < 4; t++) {
    int slot = (t << 8) + tid;
    int r = -1, a = 0;
    int h0 = HH, w0 = WW, h1 = -1, w1 = -1;
    if (slot < nc) {
      int gid = sbase + ((q & 15) << 10) + slot;
      int rr = find_c(gp, gid);
      if (rr != gid) {
        r = rr; a = ga[gid];
        unsigned int bb = gbb[gid];
        h0 = (int)(bb >> 24); w0 = (int)((bb >> 16) & 255);
        h1 = (int)((bb >> 8) & 255); w1 = (int)(bb & 255);
      }
    }
    bool pend = (r >= 0);
    while (__any(pend)) {
      unsigned long long mk = __ballot(pend);
      int srcl = (int)__ffsll(mk) - 1;
      int lead = __shfl(r, srcl);
      bool mine = pend && (r == lead);
      int v  = mine ? a  : 0;
      int g0 = mine ? h0 : HH;
      int g1 = mine ? h1 : -1;
      int g2 = mine ? w0 : WW;
      int g3 = mine ? w1 : -1;
      for (int off = 32; off > 0; off >>= 1) {
        v += __shfl_down(v, off);
        g0 = min(g0, __shfl_down(g0, off));
        g1 = max(g1, __shfl_down(g1, off));
        g2 = min(g2, __shfl_down(g2, off));
        g3 = max(g3, __shfl_down(g3, off));
      }
      int tot = __shfl(v, 0);
      int m0 = __shfl(g0, 0), m1 = __shfl(g1, 0);
      int m2 = __shfl(g2, 0), m3 = __shfl(g3, 0);
      if (lane == srcl) {
        atomicAdd(&ga[lead], tot);
        unsigned int* dst = &gbb[lead];
        unsigned int old = *dst;
        while (true) {
          int oh0 = (int)(old >> 24), ow0 = (int)((old >> 16) & 255);
          int oh1 = (int)((old >> 8) & 255), ow1 = (int)(old & 255);
          int nh0 = min(oh0, m0), nw0 = min(ow0, m2);
          int nh1 = max(oh1, m1), nw1 = max(ow1, m3);
          unsigned int mrg = ((unsigned)nh0 << 24) | ((unsigned)nw0 << 16) |
                             ((unsigned)nh1 << 8) | (unsigned)nw1;
          if (mrg == old) break;
          unsigned int got = atomicCAS(dst, old, mrg);
          if (got == old) break;
          old = got;
        }
      }
      pend = pend && !mine;
    }
  }
}

// Wide per-tile top-2 partials (cn*16): scan only the tile's nc real records.
// key = (area<<37)|((SS-lab)<<20)|slot : (area desc, label asc).
__global__ void k_top2p(const int* __restrict__ gp, const int* __restrict__ ga,
                        const unsigned short* __restrict__ gl,
                        const int* __restrict__ gnr,
                        unsigned long long* __restrict__ tt1,
                        unsigned long long* __restrict__ tt2,
                        int* __restrict__ tfs) {
  int q = blockIdx.x;
  int lm = q >> 4, tile = q & 15;
  int sbase = lm << 14;
  int nc = gnr[q];
  int tid = threadIdx.x, lane = tid & 63, wv = tid >> 6;
  unsigned long long t1 = 0, t2 = 0;
  int fsum = 0;
  for (int sl = tid; sl < nc; sl += 256) {
    int s = (tile << 10) + sl;
    int gid = sbase + s;
    if (gp[gid] == gid) {
      int a = ga[gid];
      int lab = gl[gid];
      fsum += a;
      unsigned long long key = ((unsigned long long)a << 37)
                             | ((unsigned long long)(SS - lab) << 20)
                             | (unsigned)s;
      if (key > t1) { t2 = t1; t1 = key; }
      else if (key > t2) t2 = key;
    }
  }
  for (int off = 32; off > 0; off >>= 1) {
    unsigned long long o1 = __shfl_down(t1, off), o2 = __shfl_down(t2, off);
    if (o1 > t1) { t2 = (t1 > o2) ? t1 : o2; t1 = o1; }
    else if (o1 > t2) t2 = o1;
    fsum += __shfl_down(fsum, off);
  }
  __shared__ unsigned long long s1[4], s2[4];
  __shared__ int sf[4];
  if (lane == 0) { s1[wv] = t1; s2[wv] = t2; sf[wv] = fsum; }
  __syncthreads();
  if (tid == 0) {
    for (int i = 1; i < 4; i++) {
      unsigned long long o1 = s1[i], o2 = s2[i];
      if (o1 > t1) { t2 = (t1 > o2) ? t1 : o2; t1 = o1; }
      else if (o1 > t2) t2 = o1;
      fsum += sf[i];
    }
    tt1[q] = t1; tt2[q] = t2; tfs[q] = fsum;
  }
}

// One 64-thread wave per mask: reduce 16 tile records, pick the second
// component per the exact lax.top_k candidate set, write bbox (gbb[secgid]
// already holds the fully-merged bbox thanks to k_push).
__global__ __launch_bounds__(64)
void k_mask(const double* __restrict__ tdsum,
            const unsigned int* __restrict__ tbb,
            const unsigned long long* __restrict__ tt1,
            const unsigned long long* __restrict__ tt2,
            const int* __restrict__ tfs, const int* __restrict__ gfg0,
            const unsigned int* __restrict__ gbb,
            Meta* __restrict__ mt, int c0) {
  int lm = blockIdx.x, gm = c0 + lm;
  int tid = threadIdx.x;
  int tb = lm << 4;
  double d = 0.0;
  int h0 = 255, w0 = 255, h1 = 0, w1 = 0;
  unsigned long long t1 = 0, t2 = 0;
  int fsum = 0;
  if (tid < 16) {
    d = tdsum[tb + tid];
    unsigned bb = tbb[tb + tid];
    h0 = (int)(bb >> 24); w0 = (int)((bb >> 16) & 255);
    h1 = (int)((bb >> 8) & 255); w1 = (int)(bb & 255);
    t1 = tt1[tb + tid]; t2 = tt2[tb + tid]; fsum = tfs[tb + tid];
  }
  for (int off = 8; off > 0; off >>= 1) {
    d += __shfl_down(d, off);
    h0 = min(h0, __shfl_down(h0, off));
    w0 = min(w0, __shfl_down(w0, off));
    h1 = max(h1, __shfl_down(h1, off));
    w1 = max(w1, __shfl_down(w1, off));
    unsigned long long o1 = __shfl_down(t1, off), o2 = __shfl_down(t2, off);
    if (o1 > t1) { t2 = (t1 > o2) ? t1 : o2; t1 = o1; }
    else if (o1 > t2) t2 = o1;
    fsum += __shfl_down(fsum, off);
  }
  if (tid == 0) {
    mt->dsum[gm] = d;
    unsigned long long bg = ((unsigned long long)(SS - fsum)) << 37;
    int zl = gfg0[lm] ? 1 : 0;   // best zero-area label (R5/R7 proof)
    unsigned long long zk = ((unsigned long long)(SS - zl)) << 20;
    if (bg > t1) { t2 = t1; t1 = bg; } else if (bg > t2) t2 = bg;
    if (zk > t1) { t2 = t1; t1 = zk; } else if (zk > t2) t2 = zk;
    if (t2 == bg) {
      mt->h0[gm] = h0; mt->h1[gm] = h1; mt->w0[gm] = w0; mt->w1[gm] = w1;
    } else if (t2 == zk) {
      mt->h0[gm] = 1; mt->h1[gm] = 0; mt->w0[gm] = 1; mt->w1[gm] = 0;
    } else {
      unsigned int bb = gbb[(lm << 14) + (int)(t2 & 0xFFFFF)];
      mt->h0[gm] = (int)(bb >> 24);
      mt->w0[gm] = (int)((bb >> 16) & 255);
      mt->h1[gm] = (int)((bb >> 8) & 255);
      mt->w1[gm] = (int)(bb & 255);
    }
  }
}

// 8 blocks per mask over the bbox rows; plain-store per-seg double partials.
__global__ void k_inside(const float* __restrict__ in,
                         const Meta* __restrict__ mt,
                         double* __restrict__ dinsp, int c0) {
  int b = blockIdx.x;
  int lm = b >> 3, seg = b & 7;
  int gm = c0 + lm;
  int h0 = mt->h0[gm], h1 = mt->h1[gm], w0 = mt->w0[gm], w1 = mt->w1[gm];
  double acc = 0.0;
  if (h1 >= h0) {
    int cc = w0 + threadIdx.x;
    if (cc <= w1) {
      const float* base = in + ((size_t)gm << 16);
      for (int rr = h0 + seg; rr <= h1; rr += 8) {
        float x = base[(rr << 8) + cc];
        acc += (double)fmaxf((x + 1.0f) * 0.5f, 0.0f);
      }
    }
  }
  for (int off = 32; off > 0; off >>= 1) acc += __shfl_down(acc, off);
  __shared__ double sd[4];
  int wid = threadIdx.x >> 6, lane = threadIdx.x & 63;
  if (lane == 0) sd[wid] = acc;
  __syncthreads();
  if (threadIdx.x == 0)
    dinsp[(gm << 3) + seg] = sd[0] + sd[1] + sd[2] + sd[3];
}

__global__ void k_final(const Meta* __restrict__ mt,
                        const double* __restrict__ dinsp,
                        float* __restrict__ out) {
  __shared__ double sd[NM];
  int t = threadIdx.x;
  double di = 0.0;
  for (int s = 0; s < 8; s++) di += dinsp[(t << 3) + s];
  sd[t] = (mt->dsum[t] - di) / (double)SS;
  __syncthreads();
  for (int off = 64; off > 0; off >>= 1) {
    if (t < off) sd[t] += sd[t + off];
    __syncthreads();
  }
  if (t == 0) out[0] = (float)(sd[0] / (double)NM);
}

extern "C" void kernel_launch(void* const* d_in, const int* in_sizes, int n_in,
                              void* d_out, int out_size, void* d_ws,
                              size_t ws_size, hipStream_t stream) {
  const float* in = (const float*)d_in[0];
  float* out = (float*)d_out;

  Meta* mt = (Meta*)d_ws;
  const size_t meta_bytes = (sizeof(Meta) + 255) & ~(size_t)255;
  char* base = (char*)d_ws + meta_bytes;
  size_t fixed = (size_t)NM * 8 * sizeof(double);   // dinsp (full NM)
  size_t avail = (ws_size > meta_bytes + fixed)
                     ? (ws_size - meta_bytes - fixed) : 0;
  const size_t per_mask = (size_t)NT2 * 8 + NT2 * 4 + 4 +
                          (size_t)SPM * (4 + 4 + 4 + 2) +
                          (size_t)NT2 * 512 * 2 + NT2 * 4 +
                          (size_t)NT2 * (8 + 8 + 4);   // tt1,tt2,tfs
  int chunk = (int)(avail / per_mask);
  if (chunk > NM) chunk = NM;
  if (chunk < 1) return;  // insufficient workspace (would fail validation)

  char* ptr = base;
  double* dinsp = (double*)ptr;        ptr += fixed;
  double* tdsum = (double*)ptr;        ptr += (size_t)chunk * NT2 * 8;
  unsigned long long* tt1 = (unsigned long long*)ptr;
  ptr += (size_t)chunk * NT2 * 8;
  unsigned long long* tt2 = (unsigned long long*)ptr;
  ptr += (size_t)chunk * NT2 * 8;
  int* gp = (int*)ptr;                 ptr += (size_t)chunk * SPM * 4;
  int* ga = (int*)ptr;                 ptr += (size_t)chunk * SPM * 4;
  unsigned int* gbb = (unsigned int*)ptr;       ptr += (size_t)chunk * SPM * 4;
  unsigned short* gl = (unsigned short*)ptr;    ptr += (size_t)chunk * SPM * 2;
  unsigned short* gbrow = (unsigned short*)ptr; ptr += (size_t)chunk * NT2 * 512 * 2;
  int* gnr = (int*)ptr;                ptr += (size_t)chunk * NT2 * 4;
  unsigned int* tbb = (unsigned int*)ptr;       ptr += (size_t)chunk * NT2 * 4;
  int* tfs = (int*)ptr;                ptr += (size_t)chunk * NT2 * 4;
  int* gfg0 = (int*)ptr;

  for (int c0 = 0; c0 < NM; c0 += chunk) {
    int cn = (chunk < NM - c0) ? chunk : (NM - c0);
    k_local<<<cn * NT2, 512, 0, stream>>>(in, c0, gp, ga, gbb, gl, gbrow,
                                          gnr, tdsum, tbb, gfg0);
    k_seam <<<cn * 15, 256, 0, stream>>>(gp, gbrow);
    k_push <<<cn * NT2, 256, 0, stream>>>(gp, ga, gbb, gnr);
    k_top2p<<<cn * NT2, 256, 0, stream>>>(gp, ga, gl, gnr, tt1, tt2, tfs);
    k_mask <<<cn, 64, 0, stream>>>(tdsum, tbb, tt1, tt2, tfs, gfg0, gbb,
                                   mt, c0);
    k_inside<<<cn * 8, 256, 0, stream>>>(in, mt, dinsp, c0);
  }
  k_final<<<1, 128, 0, stream>>>(mt, dinsp, out);
}